// Round 8
// baseline (411.636 us; speedup 1.0000x reference)
//
#include <hip/hip_runtime.h>

#define N_NODES 50000
#define N_EDGES 800000
#define D_FEAT  128
#define NE_ENV  4
#define EPS_F   1e-8f
#define M_CONST 4.0f   // constant softmax shift; exact max cancels in num/denom
#define NB_BUCKET 782  // ceil(50000/64) src-buckets of 64 nodes
#define BINA_EPT 16    // edges per thread in k_binA

typedef __attribute__((ext_vector_type(8))) short bf16x8;
typedef __attribute__((ext_vector_type(4))) float floatx4;
typedef __attribute__((ext_vector_type(2))) float f2v;

static __device__ __forceinline__ unsigned short f2bf(float v) {
    union { float f; unsigned int u; } c; c.f = v;
    unsigned int u = c.u;
    u += 0x7fffu + ((u >> 16) & 1u);   // round-to-nearest-even
    return (unsigned short)(u >> 16);
}

static __device__ __forceinline__ f2v bf2f2(unsigned int v) {
    f2v r;
    r.x = __uint_as_float(v << 16);
    r.y = __uint_as_float(v & 0xffff0000u);
    return r;
}

static __device__ __forceinline__ float lrelu_exp(float z) {
    float lk = z > 0.f ? z : 0.01f * z;
    return __expf(lk - M_CONST);
}

// Fused setup: blocks 0..127 -> b-vectors; 128..383 -> W swizzle; 384..3508 -> histogram
// (per-node counts AND per-bucket sums).
__global__ __launch_bounds__(256) void k_setup(const float* __restrict__ weights, const float* __restrict__ a,
        float* __restrict__ b, unsigned short* __restrict__ wsw,
        const int* __restrict__ row, int* __restrict__ counts, int* __restrict__ bsum) {
    int blk = blockIdx.x;
    if (blk < 128) {
        int wave = threadIdx.x >> 6, lane = threadIdx.x & 63;
        int t = blk * 4 + wave;   // 0..511
        int e = t >> 7, d = t & 127;
        float2 w2 = ((const float2*)(weights + e * 16384 + d * 128))[lane];
        float2 a1 = ((const float2*)(a + e * 256))[lane];
        float2 a2 = ((const float2*)(a + e * 256 + 128))[lane];
        float p1 = w2.x * a1.x + w2.y * a1.y;
        float p2 = w2.x * a2.x + w2.y * a2.y;
#pragma unroll
        for (int off = 32; off > 0; off >>= 1) {
            p1 += __shfl_xor(p1, off, 64);
            p2 += __shfl_xor(p2, off, 64);
        }
        if (lane == 0) {
            b[e * 128 + d] = p1;
            b[512 + e * 128 + d] = p2;
        }
    } else if (blk < 384) {
        // wsw[s*4096 + t*512 + l*8 + j] = Wcat[s*32 + (l>>4)*8 + j][t*16 + (l&15)]
        int idx = (blk - 128) * 256 + threadIdx.x;  // 0..65535
        int j = idx & 7;
        int l = (idx >> 3) & 63;
        int t = (idx >> 9) & 7;
        int s = idx >> 12;
        int k = s * 32 + (l >> 4) * 8 + j;
        int f = t * 16 + (l & 15);
        int e = k >> 7, d = k & 127;
        wsw[idx] = f2bf(weights[e * 16384 + d * 128 + f]);
    } else {
        int k = (blk - 384) * 256 + threadIdx.x;
        if (k < N_EDGES) {
            int s = row[k];
            atomicAdd(&counts[s], 1);
            atomicAdd(&bsum[s >> 6], 1);
        }
    }
}

// MFMA scores + x->bf16 emit. Block 782 instead scans the 782 bucket sums -> bcur/bbase.
__global__ __launch_bounds__(256) void k_s(const float* __restrict__ x, const float* __restrict__ b,
        float* __restrict__ s_src, float* __restrict__ s_dst, unsigned short* __restrict__ xbf,
        const int* __restrict__ bsum, int* __restrict__ bcur, int* __restrict__ bbase) {
    if (blockIdx.x == 782) {
        __shared__ int tsum[256];
        int t = threadIdx.x;
        int v[4]; int s = 0;
#pragma unroll
        for (int j = 0; j < 4; ++j) {
            int idx = t * 4 + j;
            v[j] = (idx < NB_BUCKET) ? bsum[idx] : 0;
            s += v[j];
        }
        tsum[t] = s;
        __syncthreads();
        for (int st = 1; st < 256; st <<= 1) {
            int add = (t >= st) ? tsum[t - st] : 0;
            __syncthreads();
            tsum[t] += add;
            __syncthreads();
        }
        int excl = tsum[t] - s;
#pragma unroll
        for (int j = 0; j < 4; ++j) {
            int idx = t * 4 + j;
            if (idx < NB_BUCKET) { bcur[idx] = excl; bbase[idx] = excl; excl += v[j]; }
        }
        return;
    }
    int wave = threadIdx.x >> 6, lane = threadIdx.x & 63;
    int gw = blockIdx.x * 4 + wave;
    if (gw >= 3125) return;
    int quad = lane >> 4, lm = lane & 15;
    int base = gw * 16;

    floatx4 acc = (floatx4){0.f, 0.f, 0.f, 0.f};
    const float* xrow = x + (size_t)(base + lm) * 128 + quad * 8;
    unsigned short* xbrow = xbf + (size_t)(base + lm) * 128 + quad * 8;

#pragma unroll
    for (int s = 0; s < 4; ++s) {
        float4 lo = *(const float4*)(xrow + s * 32);
        float4 hi = *(const float4*)(xrow + s * 32 + 4);
        bf16x8 af;
        af[0] = (short)f2bf(lo.x); af[1] = (short)f2bf(lo.y);
        af[2] = (short)f2bf(lo.z); af[3] = (short)f2bf(lo.w);
        af[4] = (short)f2bf(hi.x); af[5] = (short)f2bf(hi.y);
        af[6] = (short)f2bf(hi.z); af[7] = (short)f2bf(hi.w);
        *(bf16x8*)(xbrow + s * 32) = af;

        bf16x8 bfv = (bf16x8){0, 0, 0, 0, 0, 0, 0, 0};
        if (lm < 8) {
            const float* bp = b + lm * 128 + s * 32 + quad * 8;
            float4 b0 = *(const float4*)bp;
            float4 b1 = *(const float4*)(bp + 4);
            bfv[0] = (short)f2bf(b0.x); bfv[1] = (short)f2bf(b0.y);
            bfv[2] = (short)f2bf(b0.z); bfv[3] = (short)f2bf(b0.w);
            bfv[4] = (short)f2bf(b1.x); bfv[5] = (short)f2bf(b1.y);
            bfv[6] = (short)f2bf(b1.z); bfv[7] = (short)f2bf(b1.w);
        }
        acc = __builtin_amdgcn_mfma_f32_16x16x32_bf16(af, bfv, acc, 0, 0, 0);
    }
    if (lm < 8) {
        float* dstp = (lm < 4) ? (s_src + (size_t)(base + quad * 4) * 4 + lm)
                               : (s_dst + (size_t)(base + quad * 4) * 4 + (lm - 4));
#pragma unroll
        for (int r = 0; r < 4; ++r) dstp[r * 4] = acc[r];
    }
}

// Pass A: bin packed edges (s<<16)|d into bucket regions with contiguous per-block bursts.
__global__ __launch_bounds__(256) void k_binA(const int* __restrict__ row, const int* __restrict__ col,
        int* __restrict__ bcur, unsigned int* __restrict__ binned) {
    __shared__ int cnt[NB_BUCKET];
    __shared__ int base[NB_BUCKET];
    int t = threadIdx.x;
    for (int b = t; b < NB_BUCKET; b += 256) cnt[b] = 0;
    __syncthreads();
    unsigned int pk[BINA_EPT];
    int ebase = blockIdx.x * (256 * BINA_EPT) + t;
#pragma unroll
    for (int j = 0; j < BINA_EPT; ++j) {
        int k = ebase + j * 256;
        pk[j] = 0xffffffffu;
        if (k < N_EDGES) {
            unsigned int s = (unsigned int)row[k];
            unsigned int d = (unsigned int)col[k];
            pk[j] = (s << 16) | d;
            atomicAdd(&cnt[s >> 6], 1);
        }
    }
    __syncthreads();
    for (int b = t; b < NB_BUCKET; b += 256) {
        int c = cnt[b];
        base[b] = c ? atomicAdd(&bcur[b], c) : 0;
        cnt[b] = 0;
    }
    __syncthreads();
#pragma unroll
    for (int j = 0; j < BINA_EPT; ++j) {
        if (pk[j] != 0xffffffffu) {
            int b = pk[j] >> 22;
            int off = atomicAdd(&cnt[b], 1);
            binned[base[b] + off] = pk[j];
        }
    }
}

// Pass B (single exp pass): 64-node bucket local CSR; s_src rows in LDS; raw w out;
// den via LDS float atomics; emits mscale = ew/(den+EPS) and raw wself per node.
__global__ __launch_bounds__(256) void k_binB(const unsigned int* __restrict__ binned,
        const int* __restrict__ counts, const int* __restrict__ bbase,
        const float* __restrict__ s_src, const float* __restrict__ s_dst,
        const float* __restrict__ env_w,
        int* __restrict__ offsets, int* __restrict__ sorted_dst,
        float4* __restrict__ w_sorted, float4* __restrict__ wselfg, float4* __restrict__ mscale) {
    __shared__ int sc[64];
    __shared__ int cur[64];
    __shared__ float den[64][4];
    __shared__ float4 sal[64];
    int b = blockIdx.x;
    int nb = b << 6;
    int nc = min(64, N_NODES - nb);
    int t = threadIdx.x;
    int myc = 0;
    if (t < nc) myc = counts[nb + t];
    if (t < 64) sc[t] = myc;
    __syncthreads();
#pragma unroll
    for (int st = 1; st < 64; st <<= 1) {
        int v = 0;
        if (t < 64 && t >= st) v = sc[t - st];
        __syncthreads();
        if (t < 64) sc[t] += v;
        __syncthreads();
    }
    int base = bbase[b];
    float4 wself = {0.f, 0.f, 0.f, 0.f};
    if (t < nc) {
        int excl = base + sc[t] - myc;
        offsets[nb + t] = excl;
        cur[t] = excl;
        float4 sa = *(const float4*)(s_src + (size_t)(nb + t) * 4);
        float4 sb = *(const float4*)(s_dst + (size_t)(nb + t) * 4);
        sal[t] = sa;
        wself.x = lrelu_exp(sa.x + sb.x);
        wself.y = lrelu_exp(sa.y + sb.y);
        wself.z = lrelu_exp(sa.z + sb.z);
        wself.w = lrelu_exp(sa.w + sb.w);
        den[t][0] = wself.x; den[t][1] = wself.y;
        den[t][2] = wself.z; den[t][3] = wself.w;
    }
    __syncthreads();
    int tot = sc[63];
    int eend = base + tot;
    for (int i = base + t; i < eend; i += 256) {
        unsigned int pk = binned[i];
        int d = (int)(pk & 0xffffu);
        int ls = (int)(pk >> 16) - nb;
        float4 sa = sal[ls];
        float4 b4 = *(const float4*)(s_dst + (size_t)d * 4);
        float4 w;
        w.x = lrelu_exp(sa.x + b4.x);
        w.y = lrelu_exp(sa.y + b4.y);
        w.z = lrelu_exp(sa.z + b4.z);
        w.w = lrelu_exp(sa.w + b4.w);
        int pos = atomicAdd(&cur[ls], 1);
        sorted_dst[pos] = d;
        w_sorted[pos] = w;
        atomicAdd(&den[ls][0], w.x);
        atomicAdd(&den[ls][1], w.y);
        atomicAdd(&den[ls][2], w.z);
        atomicAdd(&den[ls][3], w.w);
    }
    __syncthreads();
    if (t < nc) {
        float4 ew = *(const float4*)(env_w + (size_t)(nb + t) * 4);
        float4 m;
        m.x = ew.x / (den[t][0] + EPS_F);
        m.y = ew.y / (den[t][1] + EPS_F);
        m.z = ew.z / (den[t][2] + EPS_F);
        m.w = ew.w / (den[t][3] + EPS_F);
        mscale[nb + t] = m;
        wselfg[nb + t] = wself;
    }
    if (b == NB_BUCKET - 1 && t == 0) offsets[N_NODES] = N_EDGES;
}

// Per-node aggregation: raw weights, epilogue scale by mscale. 8 packable fma per edge.
__global__ __launch_bounds__(256) void k_agg(const unsigned int* __restrict__ xb,
        const int* __restrict__ offsets, const int* __restrict__ sorted_dst,
        const float4* __restrict__ w_sorted, const float4* __restrict__ wselfg,
        const float4* __restrict__ mscale, unsigned short* __restrict__ Gp) {
    int wave = threadIdx.x >> 6, lane = threadIdx.x & 63;
    int n = blockIdx.x * 4 + wave;
    if (n >= N_NODES) return;

    f2v a0, a1, a2, a3;
    {
        float4 ws = wselfg[n];
        f2v xv = bf2f2(xb[(size_t)n * 64 + lane]);
        a0 = ws.x * xv; a1 = ws.y * xv; a2 = ws.z * xv; a3 = ws.w * xv;
    }

    int beg = __builtin_amdgcn_readfirstlane(offsets[n]);
    int end = __builtin_amdgcn_readfirstlane(offsets[n + 1]);
    int i = beg;
    for (; i + 3 < end; i += 4) {
        int d0 = sorted_dst[i],     d1 = sorted_dst[i + 1];
        int d2 = sorted_dst[i + 2], d3 = sorted_dst[i + 3];
        float4 c0 = w_sorted[i],     c1 = w_sorted[i + 1];
        float4 c2 = w_sorted[i + 2], c3 = w_sorted[i + 3];
        unsigned int v0 = xb[(size_t)d0 * 64 + lane];
        unsigned int v1 = xb[(size_t)d1 * 64 + lane];
        unsigned int v2 = xb[(size_t)d2 * 64 + lane];
        unsigned int v3 = xb[(size_t)d3 * 64 + lane];
        f2v x0 = bf2f2(v0), x1 = bf2f2(v1), x2 = bf2f2(v2), x3 = bf2f2(v3);
        a0 += c0.x * x0; a1 += c0.y * x0; a2 += c0.z * x0; a3 += c0.w * x0;
        a0 += c1.x * x1; a1 += c1.y * x1; a2 += c1.z * x1; a3 += c1.w * x1;
        a0 += c2.x * x2; a1 += c2.y * x2; a2 += c2.z * x2; a3 += c2.w * x2;
        a0 += c3.x * x3; a1 += c3.y * x3; a2 += c3.z * x3; a3 += c3.w * x3;
    }
    for (; i < end; ++i) {
        int d0 = sorted_dst[i];
        float4 c0 = w_sorted[i];
        f2v x0 = bf2f2(xb[(size_t)d0 * 64 + lane]);
        a0 += c0.x * x0; a1 += c0.y * x0; a2 += c0.z * x0; a3 += c0.w * x0;
    }

    float4 m4 = mscale[n];
    a0 *= m4.x; a1 *= m4.y; a2 *= m4.z; a3 *= m4.w;

    unsigned int* grow = (unsigned int*)(Gp + (size_t)n * 512);
    grow[0 * 64 + lane] = ((unsigned int)f2bf(a0.y) << 16) | f2bf(a0.x);
    grow[1 * 64 + lane] = ((unsigned int)f2bf(a1.y) << 16) | f2bf(a1.x);
    grow[2 * 64 + lane] = ((unsigned int)f2bf(a2.y) << 16) | f2bf(a2.x);
    grow[3 * 64 + lane] = ((unsigned int)f2bf(a3.y) << 16) | f2bf(a3.x);
}

// out = G'(N x 512, bf16) @ Wcat(512 x 128, bf16 pre-swizzled) + x (residual from bf16 copy).
__global__ __launch_bounds__(256) void k_gemm(const unsigned short* __restrict__ Gp,
        const unsigned short* __restrict__ Wsw,
        const unsigned short* __restrict__ xbf, float* __restrict__ out) {
    int wave = threadIdx.x >> 6, lane = threadIdx.x & 63;
    int gw = blockIdx.x * 4 + wave;
    if (gw >= 3125) return;
    int quad = lane >> 4, lm = lane & 15;
    int m = gw * 16 + lm;

    floatx4 acc[8];
#pragma unroll
    for (int t = 0; t < 8; ++t) acc[t] = (floatx4){0.f, 0.f, 0.f, 0.f};

    const unsigned short* Arow = Gp + (size_t)m * 512 + quad * 8;
#pragma unroll
    for (int s = 0; s < 16; ++s) {
        bf16x8 af = *(const bf16x8*)(Arow + s * 32);
#pragma unroll
        for (int t = 0; t < 8; ++t) {
            bf16x8 bfv = *(const bf16x8*)(Wsw + (((s * 8 + t) * 64 + lane) * 8));
            acc[t] = __builtin_amdgcn_mfma_f32_16x16x32_bf16(af, bfv, acc[t], 0, 0, 0);
        }
    }
    int row_base = gw * 16 + quad * 4;
#pragma unroll
    for (int t = 0; t < 8; ++t) {
        int colc = t * 16 + lm;
#pragma unroll
        for (int r = 0; r < 4; ++r) {
            int rowi = row_base + r;
            float xres = __uint_as_float(((unsigned int)xbf[(size_t)rowi * 128 + colc]) << 16);
            out[(size_t)rowi * 128 + colc] = acc[t][r] + xres;
        }
    }
}

extern "C" void kernel_launch(void* const* d_in, const int* in_sizes, int n_in,
                              void* d_out, int out_size, void* d_ws, size_t ws_size,
                              hipStream_t stream) {
    const float* x       = (const float*)d_in[0];
    const int*   adj     = (const int*)d_in[1];
    const int*   row     = adj;
    const int*   col     = adj + N_EDGES;
    const float* env_w   = (const float*)d_in[2];
    const float* weights = (const float*)d_in[3];
    const float* a       = (const float*)d_in[4];
    float* out = (float*)d_out;

    char* ws = (char*)d_ws;
    size_t off = 0;
    auto alloc = [&](size_t bytes) -> char* {
        char* p = ws + off;
        off += (bytes + 255) & ~(size_t)255;
        return p;
    };
    float* b          = (float*)alloc(1024 * 4);
    float* s_src      = (float*)alloc((size_t)N_NODES * 4 * 4);
    float* s_dst      = (float*)alloc((size_t)N_NODES * 4 * 4);
    int*   counts     = (int*)alloc((size_t)(N_NODES + 1024) * 4);  // counts + bsum, one memset
    int*   bsum       = counts + N_NODES;
    int*   offsets    = (int*)alloc((size_t)(N_NODES + 1) * 4);
    int*   bcur       = (int*)alloc(1024 * 4);
    int*   bbase      = (int*)alloc(1024 * 4);
    unsigned int* binned = (unsigned int*)alloc((size_t)N_EDGES * 4);
    int*   sorted_dst = (int*)alloc((size_t)N_EDGES * 4);
    float4* w_sorted  = (float4*)alloc((size_t)N_EDGES * 16);
    float4* wselfg    = (float4*)alloc((size_t)N_NODES * 16);
    float4* mscale    = (float4*)alloc((size_t)N_NODES * 16);
    unsigned short* wsw = (unsigned short*)alloc(65536 * 2);
    unsigned short* xbf = (unsigned short*)alloc((size_t)N_NODES * 128 * 2);
    unsigned short* Gp  = (unsigned short*)alloc((size_t)N_NODES * 512 * 2);

    hipMemsetAsync(counts, 0, (size_t)(N_NODES + 1024) * 4, stream);
    k_setup<<<3509, 256, 0, stream>>>(weights, a, b, wsw, row, counts, bsum);
    k_s<<<783, 256, 0, stream>>>(x, b, s_src, s_dst, xbf, bsum, bcur, bbase);
    k_binA<<<196, 256, 0, stream>>>(row, col, bcur, binned);
    k_binB<<<NB_BUCKET, 256, 0, stream>>>(binned, counts, bbase, s_src, s_dst, env_w,
                                          offsets, sorted_dst, w_sorted, wselfg, mscale);
    k_agg<<<12500, 256, 0, stream>>>((const unsigned int*)xbf, offsets, sorted_dst, w_sorted, wselfg, mscale, Gp);
    k_gemm<<<782, 256, 0, stream>>>(Gp, wsw, xbf, out);
}

// Round 9
// 232.854 us; speedup vs baseline: 1.7678x; 1.7678x over previous
//
#include <hip/hip_runtime.h>

#define N_NODES 50000
#define N_EDGES 800000
#define D_FEAT  128
#define NE_ENV  4
#define EPS_F   1e-8f
#define M_CONST 4.0f   // constant softmax shift; exact max cancels in num/denom
#define NB_BUCKET 782  // ceil(50000/64) src-buckets of 64 nodes
#define BINA_EPT 16    // edges per thread in k_binA

typedef __attribute__((ext_vector_type(8))) short bf16x8;
typedef __attribute__((ext_vector_type(4))) float floatx4;
typedef __attribute__((ext_vector_type(2))) float f2v;

static __device__ __forceinline__ unsigned short f2bf(float v) {
    union { float f; unsigned int u; } c; c.f = v;
    unsigned int u = c.u;
    u += 0x7fffu + ((u >> 16) & 1u);   // round-to-nearest-even
    return (unsigned short)(u >> 16);
}

static __device__ __forceinline__ f2v bf2f2(unsigned int v) {
    f2v r;
    r.x = __uint_as_float(v << 16);
    r.y = __uint_as_float(v & 0xffff0000u);
    return r;
}

static __device__ __forceinline__ float lrelu_exp(float z) {
    float lk = z > 0.f ? z : 0.01f * z;
    return __expf(lk - M_CONST);
}

// Fused setup: blocks 0..127 -> b-vectors; 128..383 -> W swizzle; 384..3508 -> per-node histogram.
// NOTE: no bucket-level atomics here — 800K atomics on 49 cache lines cost 216us in round 8.
__global__ __launch_bounds__(256) void k_setup(const float* __restrict__ weights, const float* __restrict__ a,
        float* __restrict__ b, unsigned short* __restrict__ wsw,
        const int* __restrict__ row, int* __restrict__ counts) {
    int blk = blockIdx.x;
    if (blk < 128) {
        int wave = threadIdx.x >> 6, lane = threadIdx.x & 63;
        int t = blk * 4 + wave;   // 0..511
        int e = t >> 7, d = t & 127;
        float2 w2 = ((const float2*)(weights + e * 16384 + d * 128))[lane];
        float2 a1 = ((const float2*)(a + e * 256))[lane];
        float2 a2 = ((const float2*)(a + e * 256 + 128))[lane];
        float p1 = w2.x * a1.x + w2.y * a1.y;
        float p2 = w2.x * a2.x + w2.y * a2.y;
#pragma unroll
        for (int off = 32; off > 0; off >>= 1) {
            p1 += __shfl_xor(p1, off, 64);
            p2 += __shfl_xor(p2, off, 64);
        }
        if (lane == 0) {
            b[e * 128 + d] = p1;
            b[512 + e * 128 + d] = p2;
        }
    } else if (blk < 384) {
        // wsw[s*4096 + t*512 + l*8 + j] = Wcat[s*32 + (l>>4)*8 + j][t*16 + (l&15)]
        int idx = (blk - 128) * 256 + threadIdx.x;  // 0..65535
        int j = idx & 7;
        int l = (idx >> 3) & 63;
        int t = (idx >> 9) & 7;
        int s = idx >> 12;
        int k = s * 32 + (l >> 4) * 8 + j;
        int f = t * 16 + (l & 15);
        int e = k >> 7, d = k & 127;
        wsw[idx] = f2bf(weights[e * 16384 + d * 128 + f]);
    } else {
        int k = (blk - 384) * 256 + threadIdx.x;
        if (k < N_EDGES) atomicAdd(&counts[row[k]], 1);
    }
}

// Bucket sums with ZERO atomics: each wave reduces its 64 counts (one bucket) via shuffle.
__global__ __launch_bounds__(256) void k_bsum(const int* __restrict__ counts, int* __restrict__ bsum) {
    int t = threadIdx.x;
    int idx = blockIdx.x * 256 + t;
    int v = (idx < N_NODES) ? counts[idx] : 0;
#pragma unroll
    for (int off = 32; off > 0; off >>= 1) v += __shfl_xor(v, off, 64);
    int bk = idx >> 6;
    if ((t & 63) == 0 && bk < NB_BUCKET) bsum[bk] = v;
}

// MFMA scores + x->bf16 emit. Block 782 instead scans the 782 bucket sums -> bcur/bbase.
__global__ __launch_bounds__(256) void k_s(const float* __restrict__ x, const float* __restrict__ b,
        float* __restrict__ s_src, float* __restrict__ s_dst, unsigned short* __restrict__ xbf,
        const int* __restrict__ bsum, int* __restrict__ bcur, int* __restrict__ bbase) {
    if (blockIdx.x == 782) {
        __shared__ int tsum[256];
        int t = threadIdx.x;
        int v[4]; int s = 0;
#pragma unroll
        for (int j = 0; j < 4; ++j) {
            int idx = t * 4 + j;
            v[j] = (idx < NB_BUCKET) ? bsum[idx] : 0;
            s += v[j];
        }
        tsum[t] = s;
        __syncthreads();
        for (int st = 1; st < 256; st <<= 1) {
            int add = (t >= st) ? tsum[t - st] : 0;
            __syncthreads();
            tsum[t] += add;
            __syncthreads();
        }
        int excl = tsum[t] - s;
#pragma unroll
        for (int j = 0; j < 4; ++j) {
            int idx = t * 4 + j;
            if (idx < NB_BUCKET) { bcur[idx] = excl; bbase[idx] = excl; excl += v[j]; }
        }
        return;
    }
    int wave = threadIdx.x >> 6, lane = threadIdx.x & 63;
    int gw = blockIdx.x * 4 + wave;
    if (gw >= 3125) return;
    int quad = lane >> 4, lm = lane & 15;
    int base = gw * 16;

    floatx4 acc = (floatx4){0.f, 0.f, 0.f, 0.f};
    const float* xrow = x + (size_t)(base + lm) * 128 + quad * 8;
    unsigned short* xbrow = xbf + (size_t)(base + lm) * 128 + quad * 8;

#pragma unroll
    for (int s = 0; s < 4; ++s) {
        float4 lo = *(const float4*)(xrow + s * 32);
        float4 hi = *(const float4*)(xrow + s * 32 + 4);
        bf16x8 af;
        af[0] = (short)f2bf(lo.x); af[1] = (short)f2bf(lo.y);
        af[2] = (short)f2bf(lo.z); af[3] = (short)f2bf(lo.w);
        af[4] = (short)f2bf(hi.x); af[5] = (short)f2bf(hi.y);
        af[6] = (short)f2bf(hi.z); af[7] = (short)f2bf(hi.w);
        *(bf16x8*)(xbrow + s * 32) = af;

        bf16x8 bfv = (bf16x8){0, 0, 0, 0, 0, 0, 0, 0};
        if (lm < 8) {
            const float* bp = b + lm * 128 + s * 32 + quad * 8;
            float4 b0 = *(const float4*)bp;
            float4 b1 = *(const float4*)(bp + 4);
            bfv[0] = (short)f2bf(b0.x); bfv[1] = (short)f2bf(b0.y);
            bfv[2] = (short)f2bf(b0.z); bfv[3] = (short)f2bf(b0.w);
            bfv[4] = (short)f2bf(b1.x); bfv[5] = (short)f2bf(b1.y);
            bfv[6] = (short)f2bf(b1.z); bfv[7] = (short)f2bf(b1.w);
        }
        acc = __builtin_amdgcn_mfma_f32_16x16x32_bf16(af, bfv, acc, 0, 0, 0);
    }
    if (lm < 8) {
        float* dstp = (lm < 4) ? (s_src + (size_t)(base + quad * 4) * 4 + lm)
                               : (s_dst + (size_t)(base + quad * 4) * 4 + (lm - 4));
#pragma unroll
        for (int r = 0; r < 4; ++r) dstp[r * 4] = acc[r];
    }
}

// Pass A: bin packed edges (s<<16)|d into bucket regions with contiguous per-block bursts.
__global__ __launch_bounds__(256) void k_binA(const int* __restrict__ row, const int* __restrict__ col,
        int* __restrict__ bcur, unsigned int* __restrict__ binned) {
    __shared__ int cnt[NB_BUCKET];
    __shared__ int base[NB_BUCKET];
    int t = threadIdx.x;
    for (int b = t; b < NB_BUCKET; b += 256) cnt[b] = 0;
    __syncthreads();
    unsigned int pk[BINA_EPT];
    int ebase = blockIdx.x * (256 * BINA_EPT) + t;
#pragma unroll
    for (int j = 0; j < BINA_EPT; ++j) {
        int k = ebase + j * 256;
        pk[j] = 0xffffffffu;
        if (k < N_EDGES) {
            unsigned int s = (unsigned int)row[k];
            unsigned int d = (unsigned int)col[k];
            pk[j] = (s << 16) | d;
            atomicAdd(&cnt[s >> 6], 1);
        }
    }
    __syncthreads();
    for (int b = t; b < NB_BUCKET; b += 256) {
        int c = cnt[b];
        base[b] = c ? atomicAdd(&bcur[b], c) : 0;
        cnt[b] = 0;
    }
    __syncthreads();
#pragma unroll
    for (int j = 0; j < BINA_EPT; ++j) {
        if (pk[j] != 0xffffffffu) {
            int b = pk[j] >> 22;
            int off = atomicAdd(&cnt[b], 1);
            binned[base[b] + off] = pk[j];
        }
    }
}

// Pass B (single exp pass): 64-node bucket local CSR; s_src rows in LDS; raw w out;
// den via LDS float atomics; emits mscale = ew/(den+EPS) and raw wself per node.
__global__ __launch_bounds__(256) void k_binB(const unsigned int* __restrict__ binned,
        const int* __restrict__ counts, const int* __restrict__ bbase,
        const float* __restrict__ s_src, const float* __restrict__ s_dst,
        const float* __restrict__ env_w,
        int* __restrict__ offsets, int* __restrict__ sorted_dst,
        float4* __restrict__ w_sorted, float4* __restrict__ wselfg, float4* __restrict__ mscale) {
    __shared__ int sc[64];
    __shared__ int cur[64];
    __shared__ float den[64][4];
    __shared__ float4 sal[64];
    int b = blockIdx.x;
    int nb = b << 6;
    int nc = min(64, N_NODES - nb);
    int t = threadIdx.x;
    int myc = 0;
    if (t < nc) myc = counts[nb + t];
    if (t < 64) sc[t] = myc;
    __syncthreads();
#pragma unroll
    for (int st = 1; st < 64; st <<= 1) {
        int v = 0;
        if (t < 64 && t >= st) v = sc[t - st];
        __syncthreads();
        if (t < 64) sc[t] += v;
        __syncthreads();
    }
    int base = bbase[b];
    float4 wself = {0.f, 0.f, 0.f, 0.f};
    if (t < nc) {
        int excl = base + sc[t] - myc;
        offsets[nb + t] = excl;
        cur[t] = excl;
        float4 sa = *(const float4*)(s_src + (size_t)(nb + t) * 4);
        float4 sb = *(const float4*)(s_dst + (size_t)(nb + t) * 4);
        sal[t] = sa;
        wself.x = lrelu_exp(sa.x + sb.x);
        wself.y = lrelu_exp(sa.y + sb.y);
        wself.z = lrelu_exp(sa.z + sb.z);
        wself.w = lrelu_exp(sa.w + sb.w);
        den[t][0] = wself.x; den[t][1] = wself.y;
        den[t][2] = wself.z; den[t][3] = wself.w;
    }
    __syncthreads();
    int tot = sc[63];
    int eend = base + tot;
    for (int i = base + t; i < eend; i += 256) {
        unsigned int pk = binned[i];
        int d = (int)(pk & 0xffffu);
        int ls = (int)(pk >> 16) - nb;
        float4 sa = sal[ls];
        float4 b4 = *(const float4*)(s_dst + (size_t)d * 4);
        float4 w;
        w.x = lrelu_exp(sa.x + b4.x);
        w.y = lrelu_exp(sa.y + b4.y);
        w.z = lrelu_exp(sa.z + b4.z);
        w.w = lrelu_exp(sa.w + b4.w);
        int pos = atomicAdd(&cur[ls], 1);
        sorted_dst[pos] = d;
        w_sorted[pos] = w;
        atomicAdd(&den[ls][0], w.x);
        atomicAdd(&den[ls][1], w.y);
        atomicAdd(&den[ls][2], w.z);
        atomicAdd(&den[ls][3], w.w);
    }
    __syncthreads();
    if (t < nc) {
        float4 ew = *(const float4*)(env_w + (size_t)(nb + t) * 4);
        float4 m;
        m.x = ew.x / (den[t][0] + EPS_F);
        m.y = ew.y / (den[t][1] + EPS_F);
        m.z = ew.z / (den[t][2] + EPS_F);
        m.w = ew.w / (den[t][3] + EPS_F);
        mscale[nb + t] = m;
        wselfg[nb + t] = wself;
    }
    if (b == NB_BUCKET - 1 && t == 0) offsets[N_NODES] = N_EDGES;
}

// Per-node aggregation: raw weights, epilogue scale by mscale. 8 packable fma per edge.
__global__ __launch_bounds__(256) void k_agg(const unsigned int* __restrict__ xb,
        const int* __restrict__ offsets, const int* __restrict__ sorted_dst,
        const float4* __restrict__ w_sorted, const float4* __restrict__ wselfg,
        const float4* __restrict__ mscale, unsigned short* __restrict__ Gp) {
    int wave = threadIdx.x >> 6, lane = threadIdx.x & 63;
    int n = blockIdx.x * 4 + wave;
    if (n >= N_NODES) return;

    f2v a0, a1, a2, a3;
    {
        float4 ws = wselfg[n];
        f2v xv = bf2f2(xb[(size_t)n * 64 + lane]);
        a0 = ws.x * xv; a1 = ws.y * xv; a2 = ws.z * xv; a3 = ws.w * xv;
    }

    int beg = __builtin_amdgcn_readfirstlane(offsets[n]);
    int end = __builtin_amdgcn_readfirstlane(offsets[n + 1]);
    int i = beg;
    for (; i + 3 < end; i += 4) {
        int d0 = sorted_dst[i],     d1 = sorted_dst[i + 1];
        int d2 = sorted_dst[i + 2], d3 = sorted_dst[i + 3];
        float4 c0 = w_sorted[i],     c1 = w_sorted[i + 1];
        float4 c2 = w_sorted[i + 2], c3 = w_sorted[i + 3];
        unsigned int v0 = xb[(size_t)d0 * 64 + lane];
        unsigned int v1 = xb[(size_t)d1 * 64 + lane];
        unsigned int v2 = xb[(size_t)d2 * 64 + lane];
        unsigned int v3 = xb[(size_t)d3 * 64 + lane];
        f2v x0 = bf2f2(v0), x1 = bf2f2(v1), x2 = bf2f2(v2), x3 = bf2f2(v3);
        a0 += c0.x * x0; a1 += c0.y * x0; a2 += c0.z * x0; a3 += c0.w * x0;
        a0 += c1.x * x1; a1 += c1.y * x1; a2 += c1.z * x1; a3 += c1.w * x1;
        a0 += c2.x * x2; a1 += c2.y * x2; a2 += c2.z * x2; a3 += c2.w * x2;
        a0 += c3.x * x3; a1 += c3.y * x3; a2 += c3.z * x3; a3 += c3.w * x3;
    }
    for (; i < end; ++i) {
        int d0 = sorted_dst[i];
        float4 c0 = w_sorted[i];
        f2v x0 = bf2f2(xb[(size_t)d0 * 64 + lane]);
        a0 += c0.x * x0; a1 += c0.y * x0; a2 += c0.z * x0; a3 += c0.w * x0;
    }

    float4 m4 = mscale[n];
    a0 *= m4.x; a1 *= m4.y; a2 *= m4.z; a3 *= m4.w;

    unsigned int* grow = (unsigned int*)(Gp + (size_t)n * 512);
    grow[0 * 64 + lane] = ((unsigned int)f2bf(a0.y) << 16) | f2bf(a0.x);
    grow[1 * 64 + lane] = ((unsigned int)f2bf(a1.y) << 16) | f2bf(a1.x);
    grow[2 * 64 + lane] = ((unsigned int)f2bf(a2.y) << 16) | f2bf(a2.x);
    grow[3 * 64 + lane] = ((unsigned int)f2bf(a3.y) << 16) | f2bf(a3.x);
}

// out = G'(N x 512, bf16) @ Wcat(512 x 128, bf16 pre-swizzled) + x (residual from bf16 copy).
__global__ __launch_bounds__(256) void k_gemm(const unsigned short* __restrict__ Gp,
        const unsigned short* __restrict__ Wsw,
        const unsigned short* __restrict__ xbf, float* __restrict__ out) {
    int wave = threadIdx.x >> 6, lane = threadIdx.x & 63;
    int gw = blockIdx.x * 4 + wave;
    if (gw >= 3125) return;
    int quad = lane >> 4, lm = lane & 15;
    int m = gw * 16 + lm;

    floatx4 acc[8];
#pragma unroll
    for (int t = 0; t < 8; ++t) acc[t] = (floatx4){0.f, 0.f, 0.f, 0.f};

    const unsigned short* Arow = Gp + (size_t)m * 512 + quad * 8;
#pragma unroll
    for (int s = 0; s < 16; ++s) {
        bf16x8 af = *(const bf16x8*)(Arow + s * 32);
#pragma unroll
        for (int t = 0; t < 8; ++t) {
            bf16x8 bfv = *(const bf16x8*)(Wsw + (((s * 8 + t) * 64 + lane) * 8));
            acc[t] = __builtin_amdgcn_mfma_f32_16x16x32_bf16(af, bfv, acc[t], 0, 0, 0);
        }
    }
    int row_base = gw * 16 + quad * 4;
#pragma unroll
    for (int t = 0; t < 8; ++t) {
        int colc = t * 16 + lm;
#pragma unroll
        for (int r = 0; r < 4; ++r) {
            int rowi = row_base + r;
            float xres = __uint_as_float(((unsigned int)xbf[(size_t)rowi * 128 + colc]) << 16);
            out[(size_t)rowi * 128 + colc] = acc[t][r] + xres;
        }
    }
}

extern "C" void kernel_launch(void* const* d_in, const int* in_sizes, int n_in,
                              void* d_out, int out_size, void* d_ws, size_t ws_size,
                              hipStream_t stream) {
    const float* x       = (const float*)d_in[0];
    const int*   adj     = (const int*)d_in[1];
    const int*   row     = adj;
    const int*   col     = adj + N_EDGES;
    const float* env_w   = (const float*)d_in[2];
    const float* weights = (const float*)d_in[3];
    const float* a       = (const float*)d_in[4];
    float* out = (float*)d_out;

    char* ws = (char*)d_ws;
    size_t off = 0;
    auto alloc = [&](size_t bytes) -> char* {
        char* p = ws + off;
        off += (bytes + 255) & ~(size_t)255;
        return p;
    };
    float* b          = (float*)alloc(1024 * 4);
    float* s_src      = (float*)alloc((size_t)N_NODES * 4 * 4);
    float* s_dst      = (float*)alloc((size_t)N_NODES * 4 * 4);
    int*   counts     = (int*)alloc((size_t)N_NODES * 4);
    int*   bsum       = (int*)alloc(1024 * 4);
    int*   offsets    = (int*)alloc((size_t)(N_NODES + 1) * 4);
    int*   bcur       = (int*)alloc(1024 * 4);
    int*   bbase      = (int*)alloc(1024 * 4);
    unsigned int* binned = (unsigned int*)alloc((size_t)N_EDGES * 4);
    int*   sorted_dst = (int*)alloc((size_t)N_EDGES * 4);
    float4* w_sorted  = (float4*)alloc((size_t)N_EDGES * 16);
    float4* wselfg    = (float4*)alloc((size_t)N_NODES * 16);
    float4* mscale    = (float4*)alloc((size_t)N_NODES * 16);
    unsigned short* wsw = (unsigned short*)alloc(65536 * 2);
    unsigned short* xbf = (unsigned short*)alloc((size_t)N_NODES * 128 * 2);
    unsigned short* Gp  = (unsigned short*)alloc((size_t)N_NODES * 512 * 2);

    hipMemsetAsync(counts, 0, (size_t)N_NODES * 4, stream);
    k_setup<<<3509, 256, 0, stream>>>(weights, a, b, wsw, row, counts);
    k_bsum<<<196, 256, 0, stream>>>(counts, bsum);
    k_s<<<783, 256, 0, stream>>>(x, b, s_src, s_dst, xbf, bsum, bcur, bbase);
    k_binA<<<196, 256, 0, stream>>>(row, col, bcur, binned);
    k_binB<<<NB_BUCKET, 256, 0, stream>>>(binned, counts, bbase, s_src, s_dst, env_w,
                                          offsets, sorted_dst, w_sorted, wselfg, mscale);
    k_agg<<<12500, 256, 0, stream>>>((const unsigned int*)xbf, offsets, sorted_dst, w_sorted, wselfg, mscale, Gp);
    k_gemm<<<782, 256, 0, stream>>>(Gp, wsw, xbf, out);
}